// Round 4
// baseline (698.928 us; speedup 1.0000x reference)
//
#include <hip/hip_runtime.h>
#include <hip/hip_bf16.h>
#include <math.h>

// ---------------- ws layout (float offsets) ----------------
#define WQ0 0
#define BQ0 320
#define WQ1 384
#define BQ1 4480
#define WQ2 4544
#define BQ2 8640
#define WQ3 8704
#define BQ3 12800
#define WQ4 12864
#define BQ4 12928
#define GT0 12932
#define GT1 13444
#define GT2 15492

__device__ void block_minmax(float mn, float mx, float* omn, float* omx) {
    __shared__ float smn[4], smx[4];
    __syncthreads();  // protect smn/smx reuse across calls
    #pragma unroll
    for (int off = 32; off > 0; off >>= 1) {
        mn = fminf(mn, __shfl_down(mn, off));
        mx = fmaxf(mx, __shfl_down(mx, off));
    }
    int wid = threadIdx.x >> 6, lane = threadIdx.x & 63;
    if (lane == 0) { smn[wid] = mn; smx[wid] = mx; }
    __syncthreads();
    if (threadIdx.x == 0) {
        float a = smn[0], b = smx[0];
        for (int i = 1; i < 4; ++i) { a = fminf(a, smn[i]); b = fmaxf(b, smx[i]); }
        smn[0] = a; smx[0] = b;
    }
    __syncthreads();
    *omn = smn[0]; *omx = smx[0];
}

// _qround forward: round((x-mn)/scale)*scale + mn, scale = max(mx-mn,1e-8)/63
__device__ void quantize_tensor(const float* __restrict__ src, int n, float* __restrict__ dst) {
    float mn = 3.4e38f, mx = -3.4e38f;
    for (int i = threadIdx.x; i < n; i += blockDim.x) {
        float v = src[i];
        mn = fminf(mn, v); mx = fmaxf(mx, v);
    }
    float gmn, gmx;
    block_minmax(mn, mx, &gmn, &gmx);
    float scale = fmaxf(gmx - gmn, 1e-8f) / 63.0f;
    for (int i = threadIdx.x; i < n; i += blockDim.x) {
        float v = src[i];
        dst[i] = rintf((v - gmn) / scale) * scale + gmn;
    }
}

__global__ void vinr_prep(
    const float* __restrict__ cb0, const float* __restrict__ ind0,
    const float* __restrict__ cb1, const float* __restrict__ ind1,
    const float* __restrict__ cb2, const float* __restrict__ ind2,
    const float* __restrict__ w0, const float* __restrict__ b0,
    const float* __restrict__ w1, const float* __restrict__ b1,
    const float* __restrict__ w2, const float* __restrict__ b2,
    const float* __restrict__ w3, const float* __restrict__ b3,
    const float* __restrict__ w4, const float* __restrict__ b4,
    float* __restrict__ ws)
{
    if (blockIdx.x == 0) {
        quantize_tensor(w0, 320, ws + WQ0);
        quantize_tensor(b0, 64, ws + BQ0);
        quantize_tensor(w1, 4096, ws + WQ1);
        quantize_tensor(b1, 64, ws + BQ1);
        quantize_tensor(w2, 4096, ws + WQ2);
        quantize_tensor(b2, 64, ws + BQ2);
        quantize_tensor(w3, 4096, ws + WQ3);
        quantize_tensor(b3, 64, ws + BQ3);
        quantize_tensor(w4, 64, ws + WQ4);
        quantize_tensor(b4, 1, ws + BQ4);
    } else {
        int r = (int)(blockIdx.x - 1) * (int)blockDim.x + (int)threadIdx.x;
        const float* ind; const float* cb; float* dst;
        if (r < 128)       { ind = ind0 + r * 64;          cb = cb0; dst = ws + GT0 + r * 4; }
        else if (r < 640)  { int rr = r - 128;  ind = ind1 + rr * 64; cb = cb1; dst = ws + GT1 + rr * 4; }
        else if (r < 2688) { int rr = r - 640;  ind = ind2 + rr * 64; cb = cb2; dst = ws + GT2 + rr * 4; }
        else return;
        // first-occurrence argmax (matches jnp.argmax tie-breaking)
        float best = -3.4e38f; int bi = 0;
        for (int j = 0; j < 64; ++j) {
            float v = ind[j];
            if (v > best) { best = v; bi = j; }
        }
        #pragma unroll
        for (int d = 0; d < 4; ++d) dst[d] = cb[bi * 4 + d];
    }
}

// Branch-free exact-gelu: 0.5*x*(1+erf(x/sqrt(2))), erf via Abramowitz-Stegun
// 7.1.26 (max abs err 1.5e-7 — far under the 6e-4 output threshold).
// ~17 straight-line VALU ops vs libm erff's branchy ~45.
// exp(y) computed as 2^(y*log2e) via v_exp_f32 (__builtin_amdgcn_exp2f).
__device__ inline float gelu_fast(float x) {
    float z  = fabsf(x) * 0.70710678118654752f;
    float t  = __builtin_amdgcn_rcpf(fmaf(0.3275911f, z, 1.0f));
    float p  = fmaf(t, 1.061405429f, -1.453152027f);
    p = fmaf(t, p, 1.421413741f);
    p = fmaf(t, p, -0.284496736f);
    p = fmaf(t, p, 0.254829592f);
    p = p * t;
    float e  = __builtin_amdgcn_exp2f(-z * z * 1.44269504088896f);  // exp(-z^2)
    float er = fmaf(-p, e, 1.0f);          // erf(|x|/sqrt2)
    er = copysignf(er, x);
    return 0.5f * x * (1.0f + er);
}

__device__ inline float tanh_fast(float x) {
    // tanh(x) = 1 - 2/(exp(2x)+1); exact limits at +-inf, ~1e-7 abs err
    float e = __builtin_amdgcn_exp2f(x * 2.88539008177793f);  // exp(2x)
    return fmaf(-2.0f, __builtin_amdgcn_rcpf(e + 1.0f), 1.0f);
}

__global__ __launch_bounds__(256) void vinr_main(
    const float* __restrict__ x, const float* __restrict__ ws,
    float* __restrict__ out, int N)
{
    int i = (int)blockIdx.x * 256 + (int)threadIdx.x;
    if (i >= N) return;
    float2 xr = ((const float2*)x)[i];
    float feat  = xr.x;
    float coord = xr.y;

    float g0 = 0.f, g1 = 0.f, g2 = 0.f, g3 = 0.f;
    const int RES[3]  = {128, 512, 2048};
    const int GOFF[3] = {GT0, GT1, GT2};
    #pragma unroll
    for (int gi = 0; gi < 3; ++gi) {
        int res = RES[gi];
        float c = (coord + 1.0f) * 0.5f * (float)(res - 1);
        int left  = min((int)floorf(c), res - 2);
        int right = max((int)ceilf(c), 1);
        float w = c - (float)left;
        const float4* gt = (const float4*)(ws + GOFF[gi]);
        float4 gl = gt[left];
        float4 gr = gt[right];
        float wm = 1.0f - w;
        g0 += wm * gl.x + w * gr.x;
        g1 += wm * gl.y + w * gr.y;
        g2 += wm * gl.z + w * gr.z;
        g3 += wm * gl.w + w * gr.w;
    }

    // layer 0: 5 -> 64 (weights wave-uniform -> scalar loads)
    float h[64];
    {
        const float* w0 = ws + WQ0;
        const float* b0 = ws + BQ0;
        #pragma unroll
        for (int j = 0; j < 64; ++j) {
            float a = b0[j];
            a = fmaf(g0,   w0[j],       a);
            a = fmaf(g1,   w0[64 + j],  a);
            a = fmaf(g2,   w0[128 + j], a);
            a = fmaf(g3,   w0[192 + j], a);
            a = fmaf(feat, w0[256 + j], a);
            h[j] = a;
        }
    }

    // layers 1..3: gelu + 64x64
    const int WOFF[3] = {WQ1, WQ2, WQ3};
    #pragma unroll 1
    for (int l = 0; l < 3; ++l) {
        const float* wl = ws + WOFF[l];
        const float* bl = wl + 4096;
        float a[64];
        #pragma unroll
        for (int k = 0; k < 64; ++k) a[k] = gelu_fast(h[k]);
        #pragma unroll
        for (int j = 0; j < 64; ++j) h[j] = bl[j];
        #pragma unroll
        for (int k = 0; k < 64; ++k) {
            float ak = a[k];
            const float* wr = wl + k * 64;
            #pragma unroll
            for (int j = 0; j < 64; ++j) h[j] = fmaf(ak, wr[j], h[j]);
        }
    }

    // layer 4: gelu + 64 -> 1, then tanh
    {
        const float* w4 = ws + WQ4;
        float acc = ws[BQ4];
        #pragma unroll
        for (int k = 0; k < 64; ++k) acc = fmaf(gelu_fast(h[k]), w4[k], acc);
        out[i] = tanh_fast(acc);
    }
}

extern "C" void kernel_launch(void* const* d_in, const int* in_sizes, int n_in,
                              void* d_out, int out_size, void* d_ws, size_t ws_size,
                              hipStream_t stream) {
    const float* x    = (const float*)d_in[0];
    const float* cb0  = (const float*)d_in[1];
    const float* ind0 = (const float*)d_in[2];
    const float* cb1  = (const float*)d_in[3];
    const float* ind1 = (const float*)d_in[4];
    const float* cb2  = (const float*)d_in[5];
    const float* ind2 = (const float*)d_in[6];
    const float* w0 = (const float*)d_in[7],  * b0 = (const float*)d_in[8];
    const float* w1 = (const float*)d_in[9],  * b1 = (const float*)d_in[10];
    const float* w2 = (const float*)d_in[11], * b2 = (const float*)d_in[12];
    const float* w3 = (const float*)d_in[13], * b3 = (const float*)d_in[14];
    const float* w4 = (const float*)d_in[15], * b4 = (const float*)d_in[16];
    float* ws  = (float*)d_ws;
    float* out = (float*)d_out;

    int N = in_sizes[0] / 2;  // 1<<20

    vinr_prep<<<12, 256, 0, stream>>>(cb0, ind0, cb1, ind1, cb2, ind2,
                                      w0, b0, w1, b1, w2, b2, w3, b3, w4, b4, ws);
    int blocks = (N + 255) / 256;
    vinr_main<<<blocks, 256, 0, stream>>>(x, ws, out, N);
}

// Round 5
// 318.249 us; speedup vs baseline: 2.1962x; 2.1962x over previous
//
#include <hip/hip_runtime.h>
#include <hip/hip_bf16.h>
#include <math.h>

// ---------------- ws layout (float offsets) ----------------
#define WQ0 0
#define BQ0 320
#define WQ1 384
#define BQ1 4480
#define WQ2 4544
#define BQ2 8640
#define WQ3 8704
#define BQ3 12800
#define WQ4 12864
#define BQ4 12928
#define GT0 12932
#define GT1 13444
#define GT2 15492
// Packed bf16 MFMA B-fragments (hi then lo), appended after grid tables.
// 24 frags (3 layers x 2 ksteps x 4 ntiles) x 64 lanes x 8 bf16 each, x2 (hi/lo)
// = 49152 bytes starting at float offset 23684 (byte 94736, 16B aligned).
#define FRAG_OFF 23684
#define NFRAG 24

typedef __bf16 bf16x8 __attribute__((ext_vector_type(8)));
typedef float floatx4 __attribute__((ext_vector_type(4)));

__device__ inline floatx4 mfma16(bf16x8 a, bf16x8 b, floatx4 c) {
    return __builtin_amdgcn_mfma_f32_16x16x32_bf16(a, b, c, 0, 0, 0);
}

__device__ void block_minmax(float mn, float mx, float* omn, float* omx) {
    __shared__ float smn[4], smx[4];
    __syncthreads();
    #pragma unroll
    for (int off = 32; off > 0; off >>= 1) {
        mn = fminf(mn, __shfl_down(mn, off));
        mx = fmaxf(mx, __shfl_down(mx, off));
    }
    int wid = threadIdx.x >> 6, lane = threadIdx.x & 63;
    if (lane == 0) { smn[wid] = mn; smx[wid] = mx; }
    __syncthreads();
    if (threadIdx.x == 0) {
        float a = smn[0], b = smx[0];
        for (int i = 1; i < 4; ++i) { a = fminf(a, smn[i]); b = fmaxf(b, smx[i]); }
        smn[0] = a; smx[0] = b;
    }
    __syncthreads();
    *omn = smn[0]; *omx = smx[0];
}

// _qround forward: round((x-mn)/scale)*scale + mn, scale = max(mx-mn,1e-8)/63
__device__ void quantize_tensor(const float* __restrict__ src, int n, float* __restrict__ dst) {
    float mn = 3.4e38f, mx = -3.4e38f;
    for (int i = threadIdx.x; i < n; i += blockDim.x) {
        float v = src[i];
        mn = fminf(mn, v); mx = fmaxf(mx, v);
    }
    float gmn, gmx;
    block_minmax(mn, mx, &gmn, &gmx);
    float scale = fmaxf(gmx - gmn, 1e-8f) / 63.0f;
    for (int i = threadIdx.x; i < n; i += blockDim.x) {
        float v = src[i];
        dst[i] = rintf((v - gmn) / scale) * scale + gmn;
    }
}

__global__ void vinr_prep(
    const float* __restrict__ cb0, const float* __restrict__ ind0,
    const float* __restrict__ cb1, const float* __restrict__ ind1,
    const float* __restrict__ cb2, const float* __restrict__ ind2,
    const float* __restrict__ w0, const float* __restrict__ b0,
    const float* __restrict__ w1, const float* __restrict__ b1,
    const float* __restrict__ w2, const float* __restrict__ b2,
    const float* __restrict__ w3, const float* __restrict__ b3,
    const float* __restrict__ w4, const float* __restrict__ b4,
    float* __restrict__ ws)
{
    if (blockIdx.x == 0) {
        quantize_tensor(w0, 320, ws + WQ0);
        quantize_tensor(b0, 64, ws + BQ0);
        quantize_tensor(w1, 4096, ws + WQ1);
        quantize_tensor(b1, 64, ws + BQ1);
        quantize_tensor(w2, 4096, ws + WQ2);
        quantize_tensor(b2, 64, ws + BQ2);
        quantize_tensor(w3, 4096, ws + WQ3);
        quantize_tensor(b3, 64, ws + BQ3);
        quantize_tensor(w4, 64, ws + WQ4);
        quantize_tensor(b4, 1, ws + BQ4);
    } else {
        int r = (int)(blockIdx.x - 1) * (int)blockDim.x + (int)threadIdx.x;
        const float* ind; const float* cb; float* dst;
        if (r < 128)       { ind = ind0 + r * 64;          cb = cb0; dst = ws + GT0 + r * 4; }
        else if (r < 640)  { int rr = r - 128;  ind = ind1 + rr * 64; cb = cb1; dst = ws + GT1 + rr * 4; }
        else if (r < 2688) { int rr = r - 640;  ind = ind2 + rr * 64; cb = cb2; dst = ws + GT2 + rr * 4; }
        else return;
        float best = -3.4e38f; int bi = 0;
        for (int j = 0; j < 64; ++j) {
            float v = ind[j];
            if (v > best) { best = v; bi = j; }
        }
        #pragma unroll
        for (int d = 0; d < 4; ++d) dst[d] = cb[bi * 4 + d];
    }
}

// Pack quantized f32 weights of layers 1..3 into per-lane MFMA B-fragments,
// split hi/lo bf16. Frag id fi = (l*2+s)*4+nt; lane holds B[k=s*32+q*8+j][n=nt*16+(lane&15)].
__global__ void vinr_prep2(float* __restrict__ ws) {
    int fi = blockIdx.x;            // 0..23
    int lane = threadIdx.x;         // 0..63
    int l = fi >> 3;
    int s = (fi >> 2) & 1;
    int nt = fi & 3;
    const int WOFF[3] = {WQ1, WQ2, WQ3};
    const float* w = ws + WOFF[l];
    int q = lane >> 4, m15 = lane & 15;
    int n = nt * 16 + m15;
    bf16x8 hi, lo;
    #pragma unroll
    for (int j = 0; j < 8; ++j) {
        int k = s * 32 + q * 8 + j;
        float v = w[k * 64 + n];
        __bf16 hb = (__bf16)v;
        hi[j] = hb;
        lo[j] = (__bf16)(v - (float)hb);
    }
    bf16x8* base = (bf16x8*)(ws + FRAG_OFF);
    base[fi * 64 + lane] = hi;
    base[NFRAG * 64 + fi * 64 + lane] = lo;
}

// Branch-free exact-gelu (AS 7.1.26 erf, abs err 1.5e-7)
__device__ inline float gelu_fast(float x) {
    float z  = fabsf(x) * 0.70710678118654752f;
    float t  = __builtin_amdgcn_rcpf(fmaf(0.3275911f, z, 1.0f));
    float p  = fmaf(t, 1.061405429f, -1.453152027f);
    p = fmaf(t, p, 1.421413741f);
    p = fmaf(t, p, -0.284496736f);
    p = fmaf(t, p, 0.254829592f);
    p = p * t;
    float e  = __builtin_amdgcn_exp2f(-z * z * 1.44269504088896f);
    float er = fmaf(-p, e, 1.0f);
    er = copysignf(er, x);
    return 0.5f * x * (1.0f + er);
}

__device__ inline float tanh_fast(float x) {
    float e = __builtin_amdgcn_exp2f(x * 2.88539008177793f);
    return fmaf(-2.0f, __builtin_amdgcn_rcpf(e + 1.0f), 1.0f);
}

// Each wave owns 64 points; activations in a private LDS tile [64][68] f32.
// Layers 1-3: 16x16x32 bf16 MFMA, hi/lo split (3 MFMAs per tile-pair).
// No __syncthreads: slices are wave-private, DS ops are in-order per wave.
#define LSTR 68

__global__ __launch_bounds__(256) void vinr_main(
    const float* __restrict__ x, const float* __restrict__ ws,
    float* __restrict__ out, int N)
{
    __shared__ __align__(16) float hlds[4 * 64 * LSTR];
    int wave = threadIdx.x >> 6, lane = threadIdx.x & 63;
    int q = lane >> 4, m15 = lane & 15;
    float* slice = hlds + wave * (64 * LSTR);

    int idx = (int)blockIdx.x * 256 + wave * 64 + lane;
    int idxc = min(idx, N - 1);
    float2 xr = ((const float2*)x)[idxc];
    float feat  = xr.x;
    float coord = xr.y;

    float g0 = 0.f, g1 = 0.f, g2 = 0.f, g3 = 0.f;
    const int RES[3]  = {128, 512, 2048};
    const int GOFF[3] = {GT0, GT1, GT2};
    #pragma unroll
    for (int gi = 0; gi < 3; ++gi) {
        int res = RES[gi];
        float c = (coord + 1.0f) * 0.5f * (float)(res - 1);
        int left  = min((int)floorf(c), res - 2);
        int right = max((int)ceilf(c), 1);
        float w = c - (float)left;
        const float4* gt = (const float4*)(ws + GOFF[gi]);
        float4 gl = gt[left];
        float4 gr = gt[right];
        float wm = 1.0f - w;
        g0 += wm * gl.x + w * gr.x;
        g1 += wm * gl.y + w * gr.y;
        g2 += wm * gl.z + w * gr.z;
        g3 += wm * gl.w + w * gr.w;
    }

    // layer 0: 5 -> 64 per-thread, then gelu, write own row to LDS
    {
        float h[64];
        const float* w0 = ws + WQ0;
        const float* b0 = ws + BQ0;
        #pragma unroll
        for (int j = 0; j < 64; ++j) {
            float a = b0[j];
            a = fmaf(g0,   w0[j],       a);
            a = fmaf(g1,   w0[64 + j],  a);
            a = fmaf(g2,   w0[128 + j], a);
            a = fmaf(g3,   w0[192 + j], a);
            a = fmaf(feat, w0[256 + j], a);
            h[j] = a;
        }
        float* row = slice + lane * LSTR;
        #pragma unroll
        for (int c = 0; c < 16; ++c) {
            float4 v;
            v.x = gelu_fast(h[4 * c + 0]);
            v.y = gelu_fast(h[4 * c + 1]);
            v.z = gelu_fast(h[4 * c + 2]);
            v.w = gelu_fast(h[4 * c + 3]);
            *(float4*)(row + 4 * c) = v;
        }
    }

    const bf16x8* fh = (const bf16x8*)(ws + FRAG_OFF);
    const bf16x8* fl = fh + NFRAG * 64;
    const int BQL[3] = {BQ1, BQ2, BQ3};

    #pragma unroll 1
    for (int l = 0; l < 3; ++l) {
        floatx4 acc[4][4];
        #pragma unroll
        for (int mt = 0; mt < 4; ++mt)
            #pragma unroll
            for (int nt = 0; nt < 4; ++nt)
                acc[mt][nt] = (floatx4){0.f, 0.f, 0.f, 0.f};

        #pragma unroll
        for (int s = 0; s < 2; ++s) {
            // A-fragments from LDS: lane holds A[m=mt*16+m15][k=s*32+q*8+j]
            bf16x8 Ah[4], Al[4];
            #pragma unroll
            for (int mt = 0; mt < 4; ++mt) {
                const float* ap = slice + (mt * 16 + m15) * LSTR + s * 32 + q * 8;
                float4 x0 = *(const float4*)ap;
                float4 x1 = *(const float4*)(ap + 4);
                float xv[8] = {x0.x, x0.y, x0.z, x0.w, x1.x, x1.y, x1.z, x1.w};
                bf16x8 ah, al;
                #pragma unroll
                for (int j = 0; j < 8; ++j) {
                    __bf16 hb = (__bf16)xv[j];
                    ah[j] = hb;
                    al[j] = (__bf16)(xv[j] - (float)hb);
                }
                Ah[mt] = ah; Al[mt] = al;
            }
            #pragma unroll
            for (int nt = 0; nt < 4; ++nt) {
                int fi = (l * 2 + s) * 4 + nt;
                bf16x8 Bh = fh[fi * 64 + lane];
                bf16x8 Bl = fl[fi * 64 + lane];
                #pragma unroll
                for (int mt = 0; mt < 4; ++mt) {
                    acc[mt][nt] = mfma16(Ah[mt], Bh, acc[mt][nt]);
                    acc[mt][nt] = mfma16(Ah[mt], Bl, acc[mt][nt]);
                    acc[mt][nt] = mfma16(Al[mt], Bh, acc[mt][nt]);
                }
            }
        }
        // epilogue: +bias, gelu, store back (C: row=q*4+r, col=m15 within tile)
        const float* bq = ws + BQL[l];
        #pragma unroll
        for (int nt = 0; nt < 4; ++nt) {
            float bias = bq[nt * 16 + m15];
            #pragma unroll
            for (int mt = 0; mt < 4; ++mt) {
                #pragma unroll
                for (int r = 0; r < 4; ++r) {
                    float v = acc[mt][nt][r] + bias;
                    slice[(mt * 16 + q * 4 + r) * LSTR + nt * 16 + m15] = gelu_fast(v);
                }
            }
        }
    }

    // layer 4: dot own row (already gelu'd) with w4, tanh
    {
        float acc4 = ws[BQ4];
        const float* w4 = ws + WQ4;
        const float* row = slice + lane * LSTR;
        #pragma unroll
        for (int c = 0; c < 16; ++c) {
            float4 v = *(const float4*)(row + 4 * c);
            acc4 = fmaf(v.x, w4[4 * c + 0], acc4);
            acc4 = fmaf(v.y, w4[4 * c + 1], acc4);
            acc4 = fmaf(v.z, w4[4 * c + 2], acc4);
            acc4 = fmaf(v.w, w4[4 * c + 3], acc4);
        }
        if (idx < N) out[idx] = tanh_fast(acc4);
    }
}

extern "C" void kernel_launch(void* const* d_in, const int* in_sizes, int n_in,
                              void* d_out, int out_size, void* d_ws, size_t ws_size,
                              hipStream_t stream) {
    const float* x    = (const float*)d_in[0];
    const float* cb0  = (const float*)d_in[1];
    const float* ind0 = (const float*)d_in[2];
    const float* cb1  = (const float*)d_in[3];
    const float* ind1 = (const float*)d_in[4];
    const float* cb2  = (const float*)d_in[5];
    const float* ind2 = (const float*)d_in[6];
    const float* w0 = (const float*)d_in[7],  * b0 = (const float*)d_in[8];
    const float* w1 = (const float*)d_in[9],  * b1 = (const float*)d_in[10];
    const float* w2 = (const float*)d_in[11], * b2 = (const float*)d_in[12];
    const float* w3 = (const float*)d_in[13], * b3 = (const float*)d_in[14];
    const float* w4 = (const float*)d_in[15], * b4 = (const float*)d_in[16];
    float* ws  = (float*)d_ws;
    float* out = (float*)d_out;

    int N = in_sizes[0] / 2;  // 1<<20

    vinr_prep<<<12, 256, 0, stream>>>(cb0, ind0, cb1, ind1, cb2, ind2,
                                      w0, b0, w1, b1, w2, b2, w3, b3, w4, b4, ws);
    vinr_prep2<<<NFRAG, 64, 0, stream>>>(ws);
    int blocks = (N + 255) / 256;
    vinr_main<<<blocks, 256, 0, stream>>>(x, ws, out, N);
}

// Round 6
// 278.998 us; speedup vs baseline: 2.5051x; 1.1407x over previous
//
#include <hip/hip_runtime.h>
#include <hip/hip_bf16.h>
#include <math.h>

// ---------------- ws layout (float offsets) ----------------
#define WQ0 0
#define BQ0 320
#define WQ1 384
#define BQ1 4480
#define WQ2 4544
#define BQ2 8640
#define WQ3 8704
#define BQ3 12800
#define WQ4 12864
#define BQ4 12928
#define GT0 12932
#define GT1 13444
#define GT2 15492
// Packed bf16 MFMA B-fragments (hi then lo): 24 frags x 64 lanes x 16B, x2.
#define FRAG_OFF 23684
#define NFRAG 24

typedef __bf16 bf16x8 __attribute__((ext_vector_type(8)));
typedef float floatx4 __attribute__((ext_vector_type(4)));
typedef float floatx2 __attribute__((ext_vector_type(2)));
typedef unsigned int uintx4 __attribute__((ext_vector_type(4)));

__device__ inline floatx4 mfma16(bf16x8 a, bf16x8 b, floatx4 c) {
    return __builtin_amdgcn_mfma_f32_16x16x32_bf16(a, b, c, 0, 0, 0);
}
__device__ inline floatx2 splat2(float c) { return (floatx2){c, c}; }
__device__ inline unsigned int fbits(float f) { return __builtin_bit_cast(unsigned int, f); }
__device__ inline float maskhi(float f) {
    return __builtin_bit_cast(float, fbits(f) & 0xffff0000u);
}
// pack two RNE-rounded bf16 into one u32 (lo in low half)
__device__ inline unsigned int pack_bf16(float a, float b) {
    unsigned short ua = __builtin_bit_cast(unsigned short, (__bf16)a);
    unsigned short ub = __builtin_bit_cast(unsigned short, (__bf16)b);
    return (unsigned int)ua | ((unsigned int)ub << 16);
}
// pack the top-16 (truncated bf16) of two floats: one v_perm_b32
__device__ inline unsigned int pack_hi2(float e0, float e1) {
    return __builtin_amdgcn_perm(fbits(e1), fbits(e0), 0x07060302u);
}

__device__ void block_minmax(float mn, float mx, float* omn, float* omx) {
    __shared__ float smn[4], smx[4];
    __syncthreads();
    #pragma unroll
    for (int off = 32; off > 0; off >>= 1) {
        mn = fminf(mn, __shfl_down(mn, off));
        mx = fmaxf(mx, __shfl_down(mx, off));
    }
    int wid = threadIdx.x >> 6, lane = threadIdx.x & 63;
    if (lane == 0) { smn[wid] = mn; smx[wid] = mx; }
    __syncthreads();
    if (threadIdx.x == 0) {
        float a = smn[0], b = smx[0];
        for (int i = 1; i < 4; ++i) { a = fminf(a, smn[i]); b = fmaxf(b, smx[i]); }
        smn[0] = a; smx[0] = b;
    }
    __syncthreads();
    *omn = smn[0]; *omx = smx[0];
}

// _qround forward: round((x-mn)/scale)*scale + mn, scale = max(mx-mn,1e-8)/63
__device__ void quantize_tensor(const float* __restrict__ src, int n, float* __restrict__ dst) {
    float mn = 3.4e38f, mx = -3.4e38f;
    for (int i = threadIdx.x; i < n; i += blockDim.x) {
        float v = src[i];
        mn = fminf(mn, v); mx = fmaxf(mx, v);
    }
    float gmn, gmx;
    block_minmax(mn, mx, &gmn, &gmx);
    float scale = fmaxf(gmx - gmn, 1e-8f) / 63.0f;
    for (int i = threadIdx.x; i < n; i += blockDim.x) {
        float v = src[i];
        dst[i] = rintf((v - gmn) / scale) * scale + gmn;
    }
}

// blocks 0..9: one quantize tensor each; blocks 10..20: grid-table rows.
__global__ void vinr_prep(
    const float* __restrict__ cb0, const float* __restrict__ ind0,
    const float* __restrict__ cb1, const float* __restrict__ ind1,
    const float* __restrict__ cb2, const float* __restrict__ ind2,
    const float* __restrict__ w0, const float* __restrict__ b0,
    const float* __restrict__ w1, const float* __restrict__ b1,
    const float* __restrict__ w2, const float* __restrict__ b2,
    const float* __restrict__ w3, const float* __restrict__ b3,
    const float* __restrict__ w4, const float* __restrict__ b4,
    float* __restrict__ ws)
{
    if (blockIdx.x < 10) {
        switch (blockIdx.x) {
            case 0: quantize_tensor(w0, 320, ws + WQ0); break;
            case 1: quantize_tensor(b0, 64, ws + BQ0); break;
            case 2: quantize_tensor(w1, 4096, ws + WQ1); break;
            case 3: quantize_tensor(b1, 64, ws + BQ1); break;
            case 4: quantize_tensor(w2, 4096, ws + WQ2); break;
            case 5: quantize_tensor(b2, 64, ws + BQ2); break;
            case 6: quantize_tensor(w3, 4096, ws + WQ3); break;
            case 7: quantize_tensor(b3, 64, ws + BQ3); break;
            case 8: quantize_tensor(w4, 64, ws + WQ4); break;
            case 9: quantize_tensor(b4, 1, ws + BQ4); break;
        }
    } else {
        int r = (int)(blockIdx.x - 10) * (int)blockDim.x + (int)threadIdx.x;
        const float* ind; const float* cb; float* dst;
        if (r < 128)       { ind = ind0 + r * 64;          cb = cb0; dst = ws + GT0 + r * 4; }
        else if (r < 640)  { int rr = r - 128;  ind = ind1 + rr * 64; cb = cb1; dst = ws + GT1 + rr * 4; }
        else if (r < 2688) { int rr = r - 640;  ind = ind2 + rr * 64; cb = cb2; dst = ws + GT2 + rr * 4; }
        else return;
        float best = -3.4e38f; int bi = 0;
        for (int j = 0; j < 64; ++j) {
            float v = ind[j];
            if (v > best) { best = v; bi = j; }
        }
        #pragma unroll
        for (int d = 0; d < 4; ++d) dst[d] = cb[bi * 4 + d];
    }
}

// Pack quantized weights (layers 1..3) into per-lane MFMA B-fragments, hi/lo RNE bf16.
__global__ void vinr_prep2(float* __restrict__ ws) {
    int fi = blockIdx.x, lane = threadIdx.x;
    int l = fi >> 3, s = (fi >> 2) & 1, nt = fi & 3;
    const int WOFF[3] = {WQ1, WQ2, WQ3};
    const float* w = ws + WOFF[l];
    int q = lane >> 4, m15 = lane & 15;
    int n = nt * 16 + m15;
    bf16x8 hi, lo;
    #pragma unroll
    for (int j = 0; j < 8; ++j) {
        int k = s * 32 + q * 8 + j;
        float v = w[k * 64 + n];
        __bf16 hb = (__bf16)v;
        hi[j] = hb;
        lo[j] = (__bf16)(v - (float)hb);
    }
    bf16x8* base = (bf16x8*)(ws + FRAG_OFF);
    base[fi * 64 + lane] = hi;
    base[NFRAG * 64 + fi * 64 + lane] = lo;
}

// Packed-pair gelu: 0.5x + 0.5|x|*erf_mag(|x|/sqrt2), AS 7.1.26 erf (1.5e-7).
// Non-transcendental ops vectorize to v_pk_*_f32 (2 FLOP/inst).
__device__ inline floatx2 gelu2(floatx2 x) {
    floatx2 ax = __builtin_elementwise_abs(x);
    floatx2 z  = ax * splat2(0.70710678118654752f);
    floatx2 den = __builtin_elementwise_fma(z, splat2(0.3275911f), splat2(1.0f));
    floatx2 t;
    t.x = __builtin_amdgcn_rcpf(den.x);
    t.y = __builtin_amdgcn_rcpf(den.y);
    floatx2 p = __builtin_elementwise_fma(t, splat2(1.061405429f), splat2(-1.453152027f));
    p = __builtin_elementwise_fma(t, p, splat2(1.421413741f));
    p = __builtin_elementwise_fma(t, p, splat2(-0.284496736f));
    p = __builtin_elementwise_fma(t, p, splat2(0.254829592f));
    p = p * t;
    floatx2 ea = (z * z) * splat2(-1.44269504088896f);
    floatx2 e;
    e.x = __builtin_amdgcn_exp2f(ea.x);
    e.y = __builtin_amdgcn_exp2f(ea.y);
    floatx2 er = __builtin_elementwise_fma(-p, e, splat2(1.0f));
    floatx2 hax = ax * splat2(0.5f);
    return __builtin_elementwise_fma(hax, er, x * splat2(0.5f));
}

__device__ inline float tanh_fast(float x) {
    float e = __builtin_amdgcn_exp2f(x * 2.88539008177793f);
    return fmaf(-2.0f, __builtin_amdgcn_rcpf(e + 1.0f), 1.0f);
}

// 32 points per wave; activations in wave-private LDS tile [32][68] f32.
// Layers 1-3: 16x16x32 bf16 MFMA hi/lo split (3 MFMA per tile-pair).
// Layer0/4 split each point's 64 features across the two lane-halves.
#define LSTR 68

__global__ __launch_bounds__(256, 4) void vinr_main(
    const float* __restrict__ x, const float* __restrict__ ws,
    float* __restrict__ out, int N)
{
    __shared__ __align__(16) float hlds[4 * 32 * LSTR];
    int wave = threadIdx.x >> 6, lane = threadIdx.x & 63;
    int q = lane >> 4, m15 = lane & 15;
    int p = lane & 31, half = lane >> 5, j0 = half << 5;
    float* slice = hlds + wave * (32 * LSTR);

    int idx = (int)blockIdx.x * 128 + wave * 32 + p;
    int idxc = min(idx, N - 1);
    float2 xr = ((const float2*)x)[idxc];
    float feat  = xr.x;
    float coord = xr.y;

    float g0 = 0.f, g1 = 0.f, g2 = 0.f, g3 = 0.f;
    const int RES[3]  = {128, 512, 2048};
    const int GOFF[3] = {GT0, GT1, GT2};
    #pragma unroll
    for (int gi = 0; gi < 3; ++gi) {
        int res = RES[gi];
        float c = (coord + 1.0f) * 0.5f * (float)(res - 1);
        int left  = min((int)floorf(c), res - 2);
        int right = max((int)ceilf(c), 1);
        float w = c - (float)left;
        const float4* gt = (const float4*)(ws + GOFF[gi]);
        float4 gl = gt[left];
        float4 gr = gt[right];
        float wm = 1.0f - w;
        g0 += wm * gl.x + w * gr.x;
        g1 += wm * gl.y + w * gr.y;
        g2 += wm * gl.z + w * gr.z;
        g3 += wm * gl.w + w * gr.w;
    }

    // layer 0: 5 -> 64; this lane computes features [j0, j0+32) of point p.
    {
        const floatx2* w0v = (const floatx2*)(ws + WQ0);  // row d pairs at d*32 + j/2
        const floatx2* b0v = (const floatx2*)(ws + BQ0);
        float* row = slice + p * LSTR + j0;
        int jh = j0 >> 1;
        #pragma unroll
        for (int jj = 0; jj < 16; ++jj) {
            floatx2 a = b0v[jh + jj];
            a = __builtin_elementwise_fma(splat2(g0),   w0v[jh + jj],        a);
            a = __builtin_elementwise_fma(splat2(g1),   w0v[32 + jh + jj],   a);
            a = __builtin_elementwise_fma(splat2(g2),   w0v[64 + jh + jj],   a);
            a = __builtin_elementwise_fma(splat2(g3),   w0v[96 + jh + jj],   a);
            a = __builtin_elementwise_fma(splat2(feat), w0v[128 + jh + jj],  a);
            *(floatx2*)(row + 2 * jj) = gelu2(a);
        }
    }

    const bf16x8* fh = (const bf16x8*)(ws + FRAG_OFF);
    const bf16x8* fl = fh + NFRAG * 64;
    const int BQL[3] = {BQ1, BQ2, BQ3};

    #pragma unroll 1
    for (int l = 0; l < 3; ++l) {
        floatx4 acc[2][4];
        #pragma unroll
        for (int mt = 0; mt < 2; ++mt)
            #pragma unroll
            for (int nt = 0; nt < 4; ++nt)
                acc[mt][nt] = (floatx4){0.f, 0.f, 0.f, 0.f};

        #pragma unroll
        for (int s = 0; s < 2; ++s) {
            // A-fragments: lane holds A[m=mt*16+m15][k=s*32+q*8+j]
            bf16x8 Ah[2], Al[2];
            #pragma unroll
            for (int mt = 0; mt < 2; ++mt) {
                const float* ap = slice + (mt * 16 + m15) * LSTR + s * 32 + q * 8;
                float4 xa = *(const float4*)ap;
                float4 xb = *(const float4*)(ap + 4);
                // hi = truncated bf16 (top 16 bits), packed pairwise via v_perm
                unsigned int h01 = pack_hi2(xa.x, xa.y);
                unsigned int h23 = pack_hi2(xa.z, xa.w);
                unsigned int h45 = pack_hi2(xb.x, xb.y);
                unsigned int h67 = pack_hi2(xb.z, xb.w);
                // lo = x - hi (exact), RNE to bf16
                unsigned int l01 = pack_bf16(xa.x - maskhi(xa.x), xa.y - maskhi(xa.y));
                unsigned int l23 = pack_bf16(xa.z - maskhi(xa.z), xa.w - maskhi(xa.w));
                unsigned int l45 = pack_bf16(xb.x - maskhi(xb.x), xb.y - maskhi(xb.y));
                unsigned int l67 = pack_bf16(xb.z - maskhi(xb.z), xb.w - maskhi(xb.w));
                Ah[mt] = __builtin_bit_cast(bf16x8, (uintx4){h01, h23, h45, h67});
                Al[mt] = __builtin_bit_cast(bf16x8, (uintx4){l01, l23, l45, l67});
            }
            #pragma unroll
            for (int nt = 0; nt < 4; ++nt) {
                int fi = (l * 2 + s) * 4 + nt;
                bf16x8 Bh = fh[fi * 64 + lane];
                bf16x8 Bl = fl[fi * 64 + lane];
                #pragma unroll
                for (int mt = 0; mt < 2; ++mt) {
                    acc[mt][nt] = mfma16(Ah[mt], Bh, acc[mt][nt]);
                    acc[mt][nt] = mfma16(Ah[mt], Bl, acc[mt][nt]);
                    acc[mt][nt] = mfma16(Al[mt], Bh, acc[mt][nt]);
                }
            }
        }
        // epilogue: +bias, gelu (packed pairs), store back.
        // C layout: row = q*4+r (point), col = m15 (feature) within tile.
        const float* bq = ws + BQL[l];
        #pragma unroll
        for (int nt = 0; nt < 4; ++nt) {
            float bias = bq[nt * 16 + m15];
            #pragma unroll
            for (int mt = 0; mt < 2; ++mt) {
                floatx4 av = acc[mt][nt];
                floatx2 v01 = gelu2((floatx2){av[0] + bias, av[1] + bias});
                floatx2 v23 = gelu2((floatx2){av[2] + bias, av[3] + bias});
                float* wbase = slice + (mt * 16 + q * 4) * LSTR + nt * 16 + m15;
                wbase[0]        = v01.x;
                wbase[LSTR]     = v01.y;
                wbase[2 * LSTR] = v23.x;
                wbase[3 * LSTR] = v23.y;
            }
        }
    }

    // layer 4: half-dot over features [j0, j0+32), combine halves via shfl.
    {
        const floatx2* w4v = (const floatx2*)(ws + WQ4);
        float acc4 = (half == 0) ? ws[BQ4] : 0.0f;
        const float* row = slice + p * LSTR + j0;
        floatx2 a2 = splat2(0.0f);
        #pragma unroll
        for (int c = 0; c < 8; ++c) {
            float4 v = *(const float4*)(row + 4 * c);
            a2 = __builtin_elementwise_fma((floatx2){v.x, v.y}, w4v[(j0 >> 1) + 2 * c],     a2);
            a2 = __builtin_elementwise_fma((floatx2){v.z, v.w}, w4v[(j0 >> 1) + 2 * c + 1], a2);
        }
        acc4 += a2.x + a2.y;
        acc4 += __shfl_xor(acc4, 32);
        if (half == 0 && idx < N) out[idx] = tanh_fast(acc4);
    }
}

extern "C" void kernel_launch(void* const* d_in, const int* in_sizes, int n_in,
                              void* d_out, int out_size, void* d_ws, size_t ws_size,
                              hipStream_t stream) {
    const float* x    = (const float*)d_in[0];
    const float* cb0  = (const float*)d_in[1];
    const float* ind0 = (const float*)d_in[2];
    const float* cb1  = (const float*)d_in[3];
    const float* ind1 = (const float*)d_in[4];
    const float* cb2  = (const float*)d_in[5];
    const float* ind2 = (const float*)d_in[6];
    const float* w0 = (const float*)d_in[7],  * b0 = (const float*)d_in[8];
    const float* w1 = (const float*)d_in[9],  * b1 = (const float*)d_in[10];
    const float* w2 = (const float*)d_in[11], * b2 = (const float*)d_in[12];
    const float* w3 = (const float*)d_in[13], * b3 = (const float*)d_in[14];
    const float* w4 = (const float*)d_in[15], * b4 = (const float*)d_in[16];
    float* ws  = (float*)d_ws;
    float* out = (float*)d_out;

    int N = in_sizes[0] / 2;  // 1<<20

    vinr_prep<<<21, 256, 0, stream>>>(cb0, ind0, cb1, ind1, cb2, ind2,
                                      w0, b0, w1, b1, w2, b2, w3, b3, w4, b4, ws);
    vinr_prep2<<<NFRAG, 64, 0, stream>>>(ws);
    int blocks = (N + 127) / 128;
    vinr_main<<<blocks, 256, 0, stream>>>(x, ws, out, N);
}